// Round 4
// baseline (656.272 us; speedup 1.0000x reference)
//
#include <hip/hip_runtime.h>
#include <math.h>
#include <stdint.h>

#define B_SZ 256
#define H_SZ 1024
#define L_SZ 10
#define V_SZ 50257

typedef __attribute__((ext_vector_type(8))) short short8;
typedef __attribute__((ext_vector_type(4))) float floatx4;

// fp32 -> bf16 bits, round-to-nearest-even (scalar)
__device__ __forceinline__ unsigned f2bf_bits(float f) {
    unsigned u = __float_as_uint(f);
    return (u + 0x7FFFu + ((u >> 16) & 1u)) >> 16;
}

// 8x fp32 -> 8x bf16 via v_cvt_pk_bf16_f32 (T12 primitive; RNE, matches f2bf_bits)
__device__ __forceinline__ short8 cvt8(float4 a, float4 b) {
    unsigned r0, r1, r2, r3;
    asm("v_cvt_pk_bf16_f32 %0, %1, %2" : "=v"(r0) : "v"(a.x), "v"(a.y));
    asm("v_cvt_pk_bf16_f32 %0, %1, %2" : "=v"(r1) : "v"(a.z), "v"(a.w));
    asm("v_cvt_pk_bf16_f32 %0, %1, %2" : "=v"(r2) : "v"(b.x), "v"(b.y));
    asm("v_cvt_pk_bf16_f32 %0, %1, %2" : "=v"(r3) : "v"(b.z), "v"(b.w));
    union { unsigned u[4]; short8 s; } u;
    u.u[0] = r0; u.u[1] = r1; u.u[2] = r2; u.u[3] = r3;
    return u.s;
}

// ---------------------------------------------------------------------------
// Barrier-free MFMA GEMM: C[M,N] = A[M,K] @ W[N,K]^T + bias (optional relu).
//
// Round-4 theory: 3 rounds of LDS/DMA/barrier staging all sat at 137-200 us
// with every pipe >80% idle -> the 2-barrier-per-chunk lockstep convoy is the
// bottleneck, not bandwidth (W is half L3-resident; A is L2-hot). So: NO LDS,
// NO barriers, NO manual waitcnt. Each wave loads its own W/A fragments
// global->VGPR; the 4 waves of a block share W-chunks through L1 (8 KB chunk,
// 32 KB L1). Compiler inserts exact counted vmcnt for register deps (only
// barriers force drains - guide m97 asm note). Waves drift freely -> TLP.
//
// Software pipeline: PD register stages, all indices compile-time static
// (#pragma unroll'd groups; rule #20). nc % PD == 0 required.
//   prologue: load chunks 0..PD-1 into stages 0..PD-1
//   main (cb += PD): compute stage p (chunk cb+p), reload stage p with
//                    chunk cb+p+PD  -> loads overlap later computes
//   tail: compute last PD stages
//
// Fragment layouts (verified, learn_hip m89/m91):
//   A/B operand: elem [row = lane&15][k = (lane>>4)*8 + j]
//   C/D:         row = (lane>>4)*4 + reg, col = lane&15
// ---------------------------------------------------------------------------
template<int MSUB, int NF, int RELU, int PD, int ABF>
__global__ __launch_bounds__(256) void gemm_direct(
    const void* __restrict__ A, const float* __restrict__ W,
    const float* __restrict__ bias, float* __restrict__ Cf,
    short* __restrict__ C16, int N, int K)
{
    const int tid  = threadIdx.x;
    const int wave = tid >> 6;
    const int lane = tid & 63;
    const int quad = lane >> 4;
    const int l16  = lane & 15;

    const int n0 = blockIdx.x * (NF * 16);
    const int m_base = blockIdx.y * (MSUB * 64) + wave * (MSUB * 16);
    const int nc = K >> 5;

    // W row pointers (clamped; epilogue masks OOB columns)
    const float* wp[NF];
#pragma unroll
    for (int nf = 0; nf < NF; ++nf) {
        int r = n0 + nf * 16 + l16;
        if (r >= N) r = N - 1;
        wp[nf] = W + (size_t)r * K + quad * 8;
    }
    const short* ab[MSUB];
    const float* af[MSUB];
#pragma unroll
    for (int ms = 0; ms < MSUB; ++ms) {
        int r = m_base + ms * 16 + l16;
        if (ABF) ab[ms] = (const short*)A + (size_t)r * K + quad * 8;
        else     af[ms] = (const float*)A + (size_t)r * K + quad * 8;
    }

    floatx4 zero = {0.f, 0.f, 0.f, 0.f};
    floatx4 acc[MSUB][NF];
#pragma unroll
    for (int ms = 0; ms < MSUB; ++ms)
#pragma unroll
        for (int nf = 0; nf < NF; ++nf) acc[ms][nf] = zero;

    // register stages (static indices only)
    float4 sw[PD][NF][2];
    short8 sa[PD][MSUB];
    float4 sf[PD][MSUB][2];

    auto lstage = [&](int p, int c) {
#pragma unroll
        for (int nf = 0; nf < NF; ++nf) {
            sw[p][nf][0] = *(const float4*)(wp[nf] + (size_t)c * 32);
            sw[p][nf][1] = *(const float4*)(wp[nf] + (size_t)c * 32 + 4);
        }
#pragma unroll
        for (int ms = 0; ms < MSUB; ++ms) {
            if constexpr (ABF) {
                sa[p][ms] = *(const short8*)(ab[ms] + (size_t)c * 32);
            } else {
                sf[p][ms][0] = *(const float4*)(af[ms] + (size_t)c * 32);
                sf[p][ms][1] = *(const float4*)(af[ms] + (size_t)c * 32 + 4);
            }
        }
    };
    auto compute = [&](int p) {
        short8 bfr[NF];
#pragma unroll
        for (int nf = 0; nf < NF; ++nf)
            bfr[nf] = cvt8(sw[p][nf][0], sw[p][nf][1]);
#pragma unroll
        for (int ms = 0; ms < MSUB; ++ms) {
            short8 afr;
            if constexpr (ABF) afr = sa[p][ms];
            else               afr = cvt8(sf[p][ms][0], sf[p][ms][1]);
#pragma unroll
            for (int nf = 0; nf < NF; ++nf)
                acc[ms][nf] = __builtin_amdgcn_mfma_f32_16x16x32_bf16(
                    afr, bfr[nf], acc[ms][nf], 0, 0, 0);
        }
    };

#pragma unroll
    for (int p = 0; p < PD; ++p) lstage(p, p);

    for (int cb = 0; cb < nc - PD; cb += PD) {
#pragma unroll
        for (int p = 0; p < PD; ++p) {
            compute(p);
            lstage(p, cb + p + PD);
        }
    }
#pragma unroll
    for (int p = 0; p < PD; ++p) compute(p);

    // ---- epilogue ----
    float bia[NF];
#pragma unroll
    for (int nf = 0; nf < NF; ++nf) {
        int n = n0 + nf * 16 + l16;
        bia[nf] = (n < N) ? bias[n] : 0.f;
    }
#pragma unroll
    for (int ms = 0; ms < MSUB; ++ms) {
        int mb = m_base + ms * 16 + quad * 4;
#pragma unroll
        for (int nf = 0; nf < NF; ++nf) {
            int n = n0 + nf * 16 + l16;
            if (n < N) {
#pragma unroll
                for (int i = 0; i < 4; ++i) {
                    float v = acc[ms][nf][i] + bia[nf];
                    if (RELU) v = fmaxf(v, 0.f);
                    if (Cf)  Cf[(size_t)(mb + i) * N + n] = v;
                    if (C16) C16[(size_t)(mb + i) * N + n] = (short)f2bf_bits(v);
                }
            }
        }
    }
}

// Two independent GEMMs (gi and gh) in ONE dispatch: blockIdx.z selects.
template<int MSUB, int NF, int RELU, int PD, int ABF>
__global__ __launch_bounds__(256) void gemm_direct_dual(
    const void* __restrict__ A0, const float* __restrict__ W0,
    const float* __restrict__ b0, float* __restrict__ C0,
    const void* __restrict__ A1, const float* __restrict__ W1,
    const float* __restrict__ b1, float* __restrict__ C1,
    int N, int K)
{
    // delegate by re-running the body inline (no LDS, so trivially shareable)
    const void*  A = blockIdx.z ? A1 : A0;
    const float* W = blockIdx.z ? W1 : W0;
    const float* b = blockIdx.z ? b1 : b0;
    float*       C = blockIdx.z ? C1 : C0;

    const int tid  = threadIdx.x;
    const int wave = tid >> 6;
    const int lane = tid & 63;
    const int quad = lane >> 4;
    const int l16  = lane & 15;
    const int n0 = blockIdx.x * (NF * 16);
    const int m_base = blockIdx.y * (MSUB * 64) + wave * (MSUB * 16);
    const int nc = K >> 5;

    const float* wp[NF];
#pragma unroll
    for (int nf = 0; nf < NF; ++nf) {
        int r = n0 + nf * 16 + l16;
        if (r >= N) r = N - 1;
        wp[nf] = W + (size_t)r * K + quad * 8;
    }
    const short* ab[MSUB];
    const float* af[MSUB];
#pragma unroll
    for (int ms = 0; ms < MSUB; ++ms) {
        int r = m_base + ms * 16 + l16;
        if (ABF) ab[ms] = (const short*)A + (size_t)r * K + quad * 8;
        else     af[ms] = (const float*)A + (size_t)r * K + quad * 8;
    }

    floatx4 zero = {0.f, 0.f, 0.f, 0.f};
    floatx4 acc[MSUB][NF];
#pragma unroll
    for (int ms = 0; ms < MSUB; ++ms)
#pragma unroll
        for (int nf = 0; nf < NF; ++nf) acc[ms][nf] = zero;

    float4 sw[PD][NF][2];
    short8 sa[PD][MSUB];
    float4 sf[PD][MSUB][2];

    auto lstage = [&](int p, int c) {
#pragma unroll
        for (int nf = 0; nf < NF; ++nf) {
            sw[p][nf][0] = *(const float4*)(wp[nf] + (size_t)c * 32);
            sw[p][nf][1] = *(const float4*)(wp[nf] + (size_t)c * 32 + 4);
        }
#pragma unroll
        for (int ms = 0; ms < MSUB; ++ms) {
            if constexpr (ABF) {
                sa[p][ms] = *(const short8*)(ab[ms] + (size_t)c * 32);
            } else {
                sf[p][ms][0] = *(const float4*)(af[ms] + (size_t)c * 32);
                sf[p][ms][1] = *(const float4*)(af[ms] + (size_t)c * 32 + 4);
            }
        }
    };
    auto compute = [&](int p) {
        short8 bfr[NF];
#pragma unroll
        for (int nf = 0; nf < NF; ++nf)
            bfr[nf] = cvt8(sw[p][nf][0], sw[p][nf][1]);
#pragma unroll
        for (int ms = 0; ms < MSUB; ++ms) {
            short8 afr;
            if constexpr (ABF) afr = sa[p][ms];
            else               afr = cvt8(sf[p][ms][0], sf[p][ms][1]);
#pragma unroll
            for (int nf = 0; nf < NF; ++nf)
                acc[ms][nf] = __builtin_amdgcn_mfma_f32_16x16x32_bf16(
                    afr, bfr[nf], acc[ms][nf], 0, 0, 0);
        }
    };

#pragma unroll
    for (int p = 0; p < PD; ++p) lstage(p, p);
    for (int cb = 0; cb < nc - PD; cb += PD) {
#pragma unroll
        for (int p = 0; p < PD; ++p) { compute(p); lstage(p, cb + p + PD); }
    }
#pragma unroll
    for (int p = 0; p < PD; ++p) compute(p);

    float bia[NF];
#pragma unroll
    for (int nf = 0; nf < NF; ++nf) {
        int n = n0 + nf * 16 + l16;
        bia[nf] = (n < N) ? b[n] : 0.f;
    }
#pragma unroll
    for (int ms = 0; ms < MSUB; ++ms) {
        int mb = m_base + ms * 16 + quad * 4;
#pragma unroll
        for (int nf = 0; nf < NF; ++nf) {
            int n = n0 + nf * 16 + l16;
            if (n < N) {
#pragma unroll
                for (int i = 0; i < 4; ++i)
                    C[(size_t)(mb + i) * N + n] = acc[ms][nf][i] + bia[nf];
            }
        }
    }
}

// ---------------------------------------------------------------------------
// Kernel 1: embedding gather + attention logits + softmax + context vector.
// Also emits bf16 copies of cat (for comb GEMM A) and hidden (for gh GEMM A).
// ---------------------------------------------------------------------------
__global__ __launch_bounds__(256) void attn_kernel(
    const int* __restrict__ tokens, const float* __restrict__ hidden,
    const float* __restrict__ enc, const float* __restrict__ emb,
    const float* __restrict__ attn_W, const float* __restrict__ attn_b,
    float* __restrict__ catf, short* __restrict__ cat16,
    short* __restrict__ h16, float* __restrict__ attn_w_out)
{
    const int b = blockIdx.x;
    const int tid = threadIdx.x;
    const int tok = tokens[b];
    const float* erow = emb + (size_t)tok * H_SZ;
    const float* hrow = hidden + (size_t)b * H_SZ;

    __shared__ float red[L_SZ][256];
    __shared__ float wts[L_SZ];

    float acc[L_SZ];
#pragma unroll
    for (int l = 0; l < L_SZ; ++l) acc[l] = 0.f;

    for (int i = tid; i < H_SZ; i += 256) {
        float e = erow[i];
        float hv = hrow[i];
        if (catf)  catf[(size_t)b * 2 * H_SZ + i] = e;
        if (cat16) cat16[(size_t)b * 2 * H_SZ + i] = (short)f2bf_bits(e);
        if (h16)   h16[(size_t)b * H_SZ + i] = (short)f2bf_bits(hv);
#pragma unroll
        for (int l = 0; l < L_SZ; ++l) {
            acc[l] += e * attn_W[l * 2 * H_SZ + i] + hv * attn_W[l * 2 * H_SZ + H_SZ + i];
        }
    }
#pragma unroll
    for (int l = 0; l < L_SZ; ++l) red[l][tid] = acc[l];
    __syncthreads();
    for (int s = 128; s > 0; s >>= 1) {
        if (tid < s) {
#pragma unroll
            for (int l = 0; l < L_SZ; ++l) red[l][tid] += red[l][tid + s];
        }
        __syncthreads();
    }
    if (tid == 0) {
        float m = -INFINITY;
        float lg[L_SZ];
#pragma unroll
        for (int l = 0; l < L_SZ; ++l) {
            lg[l] = red[l][0] + attn_b[l];
            m = fmaxf(m, lg[l]);
        }
        float s = 0.f;
#pragma unroll
        for (int l = 0; l < L_SZ; ++l) {
            float e = expf(lg[l] - m);
            wts[l] = e;
            s += e;
        }
        float inv = 1.f / s;
#pragma unroll
        for (int l = 0; l < L_SZ; ++l) {
            wts[l] *= inv;
            attn_w_out[(size_t)b * L_SZ + l] = wts[l];
        }
    }
    __syncthreads();

    for (int i = tid; i < H_SZ; i += 256) {
        float s = 0.f;
#pragma unroll
        for (int l = 0; l < L_SZ; ++l) s += wts[l] * enc[l * H_SZ + i];
        if (catf)  catf[(size_t)b * 2 * H_SZ + H_SZ + i] = s;
        if (cat16) cat16[(size_t)b * 2 * H_SZ + H_SZ + i] = (short)f2bf_bits(s);
    }
}

// ---------------------------------------------------------------------------
// GRU pointwise combine (+ optional bf16 copy of h_new for the big GEMM's A)
// ---------------------------------------------------------------------------
__global__ __launch_bounds__(256) void gru_combine(
    const float* __restrict__ gi, const float* __restrict__ gh,
    const float* __restrict__ hidden, float* __restrict__ h_new,
    short* __restrict__ hb16)
{
    int idx = blockIdx.x * blockDim.x + threadIdx.x;
    if (idx >= B_SZ * H_SZ) return;
    int b = idx >> 10;
    int j = idx & (H_SZ - 1);
    const float* gib = gi + (size_t)b * 3 * H_SZ;
    const float* ghb = gh + (size_t)b * 3 * H_SZ;
    float i_r = gib[j], i_z = gib[H_SZ + j], i_n = gib[2 * H_SZ + j];
    float h_r = ghb[j], h_z = ghb[H_SZ + j], h_n = ghb[2 * H_SZ + j];
    float r = 1.f / (1.f + expf(-(i_r + h_r)));
    float z = 1.f / (1.f + expf(-(i_z + h_z)));
    float n = tanhf(i_n + r * h_n);
    float h = hidden[idx];
    float hn = (1.f - z) * n + z * h;
    h_new[idx] = hn;
    if (hb16) hb16[idx] = (short)f2bf_bits(hn);
}

// ---------------------------------------------------------------------------
// log-softmax, 2 passes, float4, online max+sum, 4x-unrolled independent
// loads (both passes) for memory-level parallelism. One 1024-thr block/row.
// ---------------------------------------------------------------------------
__global__ __launch_bounds__(1024) void logsoftmax_v3(float* __restrict__ out)
{
    const int b = blockIdx.x;
    float* row = out + (size_t)b * V_SZ;
    const int tid = threadIdx.x;
    const int wave = tid >> 6;
    const int lane = tid & 63;

    const int head = (int)(((16u - ((uintptr_t)row & 15u)) & 15u) >> 2);  // 0..3
    const int nv = (V_SZ - head) >> 2;
    const float4* r4 = (const float4*)(row + head);
    const int tail_start = head + (nv << 2);

    float m = -INFINITY, s = 0.f;
    if (tid < head) {
        float v = row[tid];
        m = v; s = 1.f;
    }
    int i = tid;
    for (; i + 3072 < nv; i += 4096) {
        float4 v0 = r4[i], v1 = r4[i + 1024], v2 = r4[i + 2048], v3 = r4[i + 3072];
        float m0 = fmaxf(fmaxf(v0.x, v0.y), fmaxf(v0.z, v0.w));
        float m1 = fmaxf(fmaxf(v1.x, v1.y), fmaxf(v1.z, v1.w));
        float m2 = fmaxf(fmaxf(v2.x, v2.y), fmaxf(v2.z, v2.w));
        float m3 = fmaxf(fmaxf(v3.x, v3.y), fmaxf(v3.z, v3.w));
        float mv = fmaxf(fmaxf(m0, m1), fmaxf(m2, m3));
        if (mv > m) { s *= expf(m - mv); m = mv; }
        s += expf(v0.x - m) + expf(v0.y - m) + expf(v0.z - m) + expf(v0.w - m);
        s += expf(v1.x - m) + expf(v1.y - m) + expf(v1.z - m) + expf(v1.w - m);
        s += expf(v2.x - m) + expf(v2.y - m) + expf(v2.z - m) + expf(v2.w - m);
        s += expf(v3.x - m) + expf(v3.y - m) + expf(v3.z - m) + expf(v3.w - m);
    }
    for (; i < nv; i += 1024) {
        float4 v = r4[i];
        float mv = fmaxf(fmaxf(v.x, v.y), fmaxf(v.z, v.w));
        if (mv > m) { s *= expf(m - mv); m = mv; }
        s += expf(v.x - m) + expf(v.y - m) + expf(v.z - m) + expf(v.w - m);
    }
    for (int t = tail_start + tid; t < V_SZ; t += 1024) {
        float v = row[t];
        if (v > m) { s *= expf(m - v); m = v; }
        s += expf(v - m);
    }

    for (int off = 32; off > 0; off >>= 1) {
        float m2 = __shfl_down(m, off);
        float s2 = __shfl_down(s, off);
        float mn = fmaxf(m, m2);
        s = s * expf(m - mn) + s2 * expf(m2 - mn);
        m = mn;
    }
    __shared__ float smax[16], ssum[16], slse;
    if (lane == 0) { smax[wave] = m; ssum[wave] = s; }
    __syncthreads();
    if (tid == 0) {
        float M = smax[0], S = ssum[0];
        for (int w = 1; w < 16; ++w) {
            float mn = fmaxf(M, smax[w]);
            S = S * expf(M - mn) + ssum[w] * expf(smax[w] - mn);
            M = mn;
        }
        slse = M + logf(S);
    }
    __syncthreads();
    const float lse = slse;

    if (tid < head) row[tid] -= lse;
    float4* w4 = (float4*)(row + head);
    i = tid;
    for (; i + 3072 < nv; i += 4096) {
        float4 v0 = r4[i], v1 = r4[i + 1024], v2 = r4[i + 2048], v3 = r4[i + 3072];
        v0.x -= lse; v0.y -= lse; v0.z -= lse; v0.w -= lse;
        v1.x -= lse; v1.y -= lse; v1.z -= lse; v1.w -= lse;
        v2.x -= lse; v2.y -= lse; v2.z -= lse; v2.w -= lse;
        v3.x -= lse; v3.y -= lse; v3.z -= lse; v3.w -= lse;
        w4[i] = v0; w4[i + 1024] = v1; w4[i + 2048] = v2; w4[i + 3072] = v3;
    }
    for (; i < nv; i += 1024) {
        float4 v = r4[i];
        v.x -= lse; v.y -= lse; v.z -= lse; v.w -= lse;
        w4[i] = v;
    }
    for (int t = tail_start + tid; t < V_SZ; t += 1024) row[t] -= lse;
}

// ---------------------------------------------------------------------------
extern "C" void kernel_launch(void* const* d_in, const int* in_sizes, int n_in,
                              void* d_out, int out_size, void* d_ws, size_t ws_size,
                              hipStream_t stream)
{
    const int*   tokens = (const int*)d_in[0];
    const float* hidden = (const float*)d_in[1];
    const float* enc    = (const float*)d_in[2];
    const float* emb    = (const float*)d_in[3];
    const float* attn_W = (const float*)d_in[4];
    const float* attn_b = (const float*)d_in[5];
    const float* comb_W = (const float*)d_in[6];
    const float* comb_b = (const float*)d_in[7];
    const float* W_ih   = (const float*)d_in[8];
    const float* W_hh   = (const float*)d_in[9];
    const float* b_ih   = (const float*)d_in[10];
    const float* b_hh   = (const float*)d_in[11];
    const float* out_W  = (const float*)d_in[12];
    const float* out_b  = (const float*)d_in[13];

    float* out = (float*)d_out;
    float* logits     = out;                                   // [B,V]
    float* h_new      = out + (size_t)B_SZ * V_SZ;             // [B,H]
    float* attn_w_out = h_new + (size_t)B_SZ * H_SZ;           // [B,L]

    // Workspace: bf16 A-operands (cat16, x16, hin16, hb16) + fp32 gi/gh.
    const size_t need = (size_t)B_SZ * 5 * H_SZ * sizeof(short)
                      + (size_t)B_SZ * 6 * H_SZ * sizeof(float);
    const bool use_ws = (d_ws != nullptr) && (ws_size >= need);

    if (use_ws) {
        short* cat16 = (short*)d_ws;                               // [B,2H]
        short* x16   = cat16 + (size_t)B_SZ * 2 * H_SZ;            // [B,H]
        short* hin16 = x16   + (size_t)B_SZ * H_SZ;                // [B,H]
        short* hb16  = hin16 + (size_t)B_SZ * H_SZ;                // [B,H]
        float* gi    = (float*)(hb16 + (size_t)B_SZ * H_SZ);       // [B,3H]
        float* gh    = gi + (size_t)B_SZ * 3 * H_SZ;               // [B,3H]

        attn_kernel<<<B_SZ, 256, 0, stream>>>(tokens, hidden, enc, emb, attn_W,
                                              attn_b, nullptr, cat16, hin16,
                                              attn_w_out);
        // x16 = bf16(relu(cat @ comb_W^T + comb_b))   [256 x 1024, K=2048]
        gemm_direct<1, 2, 1, 4, 1><<<dim3(H_SZ / 32, 4), 256, 0, stream>>>(
            cat16, comb_W, comb_b, nullptr, x16, H_SZ, 2 * H_SZ);
        // gi = x @ W_ih^T + b_ih ; gh = h @ W_hh^T + b_hh   (one dispatch)
        gemm_direct_dual<1, 2, 0, 4, 1><<<dim3(3 * H_SZ / 32, 4, 2), 256, 0, stream>>>(
            x16, W_ih, b_ih, gi, hin16, W_hh, b_hh, gh, 3 * H_SZ, H_SZ);
        gru_combine<<<(B_SZ * H_SZ + 255) / 256, 256, 0, stream>>>(
            gi, gh, hidden, h_new, hb16);
        // logits = h_new @ out_W^T + out_b            [256 x 50257, K=1024]
        gemm_direct<4, 4, 0, 2, 1><<<dim3((V_SZ + 63) / 64, 1), 256, 0, stream>>>(
            hb16, out_W, out_b, logits, nullptr, V_SZ, H_SZ);
    } else {
        // Fallback: fp32 scratch carved from logits region (dead before the
        // big GEMM); big GEMM reads h_new (output region, safe) as fp32 A.
        float* cat = logits;                           // [B,2H]
        float* x   = cat + (size_t)B_SZ * 2 * H_SZ;    // [B,H]
        float* gi  = x   + (size_t)B_SZ * H_SZ;        // [B,3H]
        float* gh  = gi  + (size_t)B_SZ * 3 * H_SZ;    // [B,3H]

        attn_kernel<<<B_SZ, 256, 0, stream>>>(tokens, hidden, enc, emb, attn_W,
                                              attn_b, cat, nullptr, nullptr,
                                              attn_w_out);
        gemm_direct<1, 2, 1, 4, 0><<<dim3(H_SZ / 32, 4), 256, 0, stream>>>(
            cat, comb_W, comb_b, x, nullptr, H_SZ, 2 * H_SZ);
        gemm_direct_dual<1, 2, 0, 4, 0><<<dim3(3 * H_SZ / 32, 4, 2), 256, 0, stream>>>(
            x, W_ih, b_ih, gi, hidden, W_hh, b_hh, gh, 3 * H_SZ, H_SZ);
        gru_combine<<<(B_SZ * H_SZ + 255) / 256, 256, 0, stream>>>(
            gi, gh, hidden, h_new, nullptr);
        gemm_direct<4, 4, 0, 2, 0><<<dim3((V_SZ + 63) / 64, 1), 256, 0, stream>>>(
            h_new, out_W, out_b, logits, nullptr, V_SZ, H_SZ);
    }
    logsoftmax_v3<<<B_SZ, 1024, 0, stream>>>(logits);
}

// Round 5
// 588.829 us; speedup vs baseline: 1.1145x; 1.1145x over previous
//
#include <hip/hip_runtime.h>
#include <math.h>
#include <stdint.h>

#define B_SZ 256
#define H_SZ 1024
#define L_SZ 10
#define V_SZ 50257

typedef __attribute__((ext_vector_type(8))) short short8;
typedef __attribute__((ext_vector_type(4))) float floatx4;

// fp32 -> bf16 bits, round-to-nearest-even (scalar)
__device__ __forceinline__ unsigned f2bf_bits(float f) {
    unsigned u = __float_as_uint(f);
    return (u + 0x7FFFu + ((u >> 16) & 1u)) >> 16;
}

// 8x fp32 -> 8x bf16 via v_cvt_pk_bf16_f32 (RNE, matches f2bf_bits)
__device__ __forceinline__ short8 cvt8(float4 a, float4 b) {
    unsigned r0, r1, r2, r3;
    asm("v_cvt_pk_bf16_f32 %0, %1, %2" : "=v"(r0) : "v"(a.x), "v"(a.y));
    asm("v_cvt_pk_bf16_f32 %0, %1, %2" : "=v"(r1) : "v"(a.z), "v"(a.w));
    asm("v_cvt_pk_bf16_f32 %0, %1, %2" : "=v"(r2) : "v"(b.x), "v"(b.y));
    asm("v_cvt_pk_bf16_f32 %0, %1, %2" : "=v"(r3) : "v"(b.z), "v"(b.w));
    union { unsigned u[4]; short8 s; } u;
    u.u[0] = r0; u.u[1] = r1; u.u[2] = r2; u.u[3] = r3;
    return u.s;
}

// 4x fp32 -> 4x bf16 packed (8B)
__device__ __forceinline__ uint2 pk4(float4 v) {
    uint2 r;
    asm("v_cvt_pk_bf16_f32 %0, %1, %2" : "=v"(r.x) : "v"(v.x), "v"(v.y));
    asm("v_cvt_pk_bf16_f32 %0, %1, %2" : "=v"(r.y) : "v"(v.z), "v"(v.w));
    return r;
}

// ---------------------------------------------------------------------------
// Panel-staged MFMA GEMM: C[M,N] = A[M,K] @ W[N,K]^T + bias (optional relu).
//
// Round-5 theory: all prior structures were HBM-PATTERN-bound (~1 TB/s
// delivered: 128B slivers per 4KB-strided W row thrash DRAM pages). Fix:
// each block stages ONE W panel (PROWS=NF*16 rows x full K) fp32->bf16 into
// 64 KB LDS via FULLY CONTIGUOUS float4 sweeps (4 KB/instr streaming), then
// runs the whole K-loop from LDS with ZERO in-loop barriers (LDS read-only
// after one __syncthreads; waves drift freely). W is read from HBM exactly
// once, streaming. A (bf16, L2-hot) is register-prefetched 2 chunks deep.
// 64 KB LDS -> 2 blocks/CU: the second block's staging overlaps the first's
// compute (natural cross-block pipelining, no explicit dbuf).
//
// LDS swizzle (G4): logical [PROWS][K] bf16; physical byte =
//   row*(2K) + (kbyte ^ ((row&7)<<4)).
// Write side: row-uniform per wave -> XOR uniform -> baseline b128 banking.
// Read side: lanes (l16,quad) spread 8 lanes/granule = b128 baseline, no
// extra conflicts (3-bit XOR required: rows alias banks at 2KB stride).
// Fragment layouts (verified, learn_hip m89/m91):
//   A/B operand: elem [row = lane&15][k = (lane>>4)*8 + j]
//   C/D:         row = (lane>>4)*4 + reg, col = lane&15
// ---------------------------------------------------------------------------
template<int MSUB, int NF, int KK, int RELU, int ABF>
__device__ __forceinline__ void panel_body(
    short* lds,
    const void* __restrict__ A, const float* __restrict__ W,
    const float* __restrict__ bias, float* __restrict__ Cf,
    short* __restrict__ C16, int N)
{
    constexpr int PROWS = NF * 16;
    constexpr int NC = KK / 32;

    const int tid  = threadIdx.x;
    const int wave = tid >> 6;
    const int lane = tid & 63;
    const int quad = lane >> 4;
    const int l16  = lane & 15;

    const int n0 = blockIdx.x * PROWS;
    const int m_base = blockIdx.y * (MSUB * 64) + wave * (MSUB * 16);

    // ---- stage W panel: contiguous fp32 read -> bf16 swizzled LDS ----
    constexpr int ITERS = PROWS * KK / 2048;   // 16 for all configs
#pragma unroll
    for (int it = 0; it < ITERS; ++it) {
        int e   = it * 2048 + tid * 8;
        int row = e / KK;
        int k   = e % KK;
        int gr  = n0 + row;
        if (gr >= N) gr = N - 1;               // clamp; epilogue masks
        const float* src = W + (size_t)gr * KK + k;
        float4 a0 = *(const float4*)src;
        float4 a1 = *(const float4*)(src + 4);
        int pb = row * (KK * 2) + ((k * 2) ^ ((row & 7) << 4));
        *(short8*)((char*)lds + pb) = cvt8(a0, a1);
    }
    __syncthreads();

    // ---- A pointers ----
    const short* ab[MSUB];
    const float* af[MSUB];
#pragma unroll
    for (int ms = 0; ms < MSUB; ++ms) {
        int r = m_base + ms * 16 + l16;
        if (ABF) ab[ms] = (const short*)A + (size_t)r * KK + quad * 8;
        else     af[ms] = (const float*)A + (size_t)r * KK + quad * 8;
    }

    int rb[NF];
#pragma unroll
    for (int nf = 0; nf < NF; ++nf) rb[nf] = (nf * 16 + l16) * (KK * 2);
    const int r7x = (l16 & 7) << 4;

    floatx4 zero = {0.f, 0.f, 0.f, 0.f};
    floatx4 acc[MSUB][NF];
#pragma unroll
    for (int ms = 0; ms < MSUB; ++ms)
#pragma unroll
        for (int nf = 0; nf < NF; ++nf) acc[ms][nf] = zero;

    auto loadA = [&](short8* s, int c) {
#pragma unroll
        for (int ms = 0; ms < MSUB; ++ms) {
            if constexpr (ABF) {
                s[ms] = *(const short8*)(ab[ms] + c * 32);
            } else {
                float4 a0 = *(const float4*)(af[ms] + c * 32);
                float4 a1 = *(const float4*)(af[ms] + c * 32 + 4);
                s[ms] = cvt8(a0, a1);
            }
        }
    };
    auto comp = [&](const short8* s, int c) {
        short8 bfr[NF];
#pragma unroll
        for (int nf = 0; nf < NF; ++nf) {
            int kb = (c * 64 + quad * 16) ^ r7x;
            bfr[nf] = *(const short8*)((char*)lds + rb[nf] + kb);
        }
#pragma unroll
        for (int ms = 0; ms < MSUB; ++ms)
#pragma unroll
            for (int nf = 0; nf < NF; ++nf)
                acc[ms][nf] = __builtin_amdgcn_mfma_f32_16x16x32_bf16(
                    s[ms], bfr[nf], acc[ms][nf], 0, 0, 0);
    };

    // ---- K-loop: no barriers; A prefetched 2 chunks deep ----
    short8 s0[MSUB], s1[MSUB];
    loadA(s0, 0);
    loadA(s1, 1);
#pragma unroll
    for (int cc = 0; cc < NC; cc += 2) {
        short8 n0s[MSUB], n1s[MSUB];
        if (cc + 2 < NC) loadA(n0s, cc + 2);
        if (cc + 3 < NC) loadA(n1s, cc + 3);
        comp(s0, cc);
        comp(s1, cc + 1);
        if (cc + 2 < NC) {
#pragma unroll
            for (int ms = 0; ms < MSUB; ++ms) { s0[ms] = n0s[ms]; s1[ms] = n1s[ms]; }
        }
    }

    // ---- epilogue ----
    float bia[NF];
#pragma unroll
    for (int nf = 0; nf < NF; ++nf) {
        int n = n0 + nf * 16 + l16;
        bia[nf] = (n < N) ? bias[n] : 0.f;
    }
#pragma unroll
    for (int ms = 0; ms < MSUB; ++ms) {
        int mb = m_base + ms * 16 + quad * 4;
#pragma unroll
        for (int nf = 0; nf < NF; ++nf) {
            int n = n0 + nf * 16 + l16;
            if (n < N) {
#pragma unroll
                for (int i = 0; i < 4; ++i) {
                    float v = acc[ms][nf][i] + bia[nf];
                    if (RELU) v = fmaxf(v, 0.f);
                    if (Cf)  Cf[(size_t)(mb + i) * N + n] = v;
                    if (C16) C16[(size_t)(mb + i) * N + n] = (short)f2bf_bits(v);
                }
            }
        }
    }
}

template<int MSUB, int NF, int KK, int RELU, int ABF>
__global__ __launch_bounds__(256) void gemm_panel(
    const void* __restrict__ A, const float* __restrict__ W,
    const float* __restrict__ bias, float* __restrict__ Cf,
    short* __restrict__ C16, int N)
{
    __shared__ __align__(16) short lds[NF * 16 * KK];   // 64 KB
    panel_body<MSUB, NF, KK, RELU, ABF>(lds, A, W, bias, Cf, C16, N);
}

// gi and gh in one dispatch: blockIdx.z selects.
template<int MSUB, int NF, int KK, int ABF>
__global__ __launch_bounds__(256) void gemm_panel_dual(
    const void* __restrict__ A0, const float* __restrict__ W0,
    const float* __restrict__ b0, float* __restrict__ C0,
    const void* __restrict__ A1, const float* __restrict__ W1,
    const float* __restrict__ b1, float* __restrict__ C1, int N)
{
    __shared__ __align__(16) short lds[NF * 16 * KK];
    const void*  A = blockIdx.z ? A1 : A0;
    const float* W = blockIdx.z ? W1 : W0;
    const float* b = blockIdx.z ? b1 : b0;
    float*       C = blockIdx.z ? C1 : C0;
    panel_body<MSUB, NF, KK, 0, ABF>(lds, A, W, b, C, nullptr, N);
}

// ---------------------------------------------------------------------------
// Kernel 1: embedding gather + attention logits + softmax + context vector.
// Vectorized: H=1024 -> exactly one float4 per thread (256 threads).
// ---------------------------------------------------------------------------
__global__ __launch_bounds__(256) void attn_kernel(
    const int* __restrict__ tokens, const float* __restrict__ hidden,
    const float* __restrict__ enc, const float* __restrict__ emb,
    const float* __restrict__ attn_W, const float* __restrict__ attn_b,
    float* __restrict__ catf, short* __restrict__ cat16,
    short* __restrict__ h16, float* __restrict__ attn_w_out)
{
    const int b   = blockIdx.x;
    const int tid = threadIdx.x;
    const int tok = tokens[b];

    const float4* e4 = (const float4*)(emb + (size_t)tok * H_SZ);
    const float4* h4 = (const float4*)(hidden + (size_t)b * H_SZ);
    const float4* w4 = (const float4*)attn_W;         // [L][512]
    float4 e = e4[tid];
    float4 h = h4[tid];

    if (catf)  ((float4*)(catf + (size_t)b * 2 * H_SZ))[tid] = e;
    if (cat16) ((uint2*)(cat16 + (size_t)b * 2 * H_SZ))[tid] = pk4(e);
    if (h16)   ((uint2*)(h16 + (size_t)b * H_SZ))[tid] = pk4(h);

    float acc[L_SZ];
#pragma unroll
    for (int l = 0; l < L_SZ; ++l) {
        float4 we = w4[l * 512 + tid];
        float4 wh = w4[l * 512 + 256 + tid];
        acc[l] = e.x * we.x + e.y * we.y + e.z * we.z + e.w * we.w
               + h.x * wh.x + h.y * wh.y + h.z * wh.z + h.w * wh.w;
    }

    __shared__ float red[L_SZ][256];
    __shared__ float wts[L_SZ];
#pragma unroll
    for (int l = 0; l < L_SZ; ++l) red[l][tid] = acc[l];
    __syncthreads();
    for (int s = 128; s > 0; s >>= 1) {
        if (tid < s) {
#pragma unroll
            for (int l = 0; l < L_SZ; ++l) red[l][tid] += red[l][tid + s];
        }
        __syncthreads();
    }
    if (tid == 0) {
        float m = -INFINITY;
        float lg[L_SZ];
#pragma unroll
        for (int l = 0; l < L_SZ; ++l) {
            lg[l] = red[l][0] + attn_b[l];
            m = fmaxf(m, lg[l]);
        }
        float s = 0.f;
#pragma unroll
        for (int l = 0; l < L_SZ; ++l) {
            float ev = expf(lg[l] - m);
            wts[l] = ev;
            s += ev;
        }
        float inv = 1.f / s;
#pragma unroll
        for (int l = 0; l < L_SZ; ++l) {
            wts[l] *= inv;
            attn_w_out[(size_t)b * L_SZ + l] = wts[l];
        }
    }
    __syncthreads();

    float4 s = {0.f, 0.f, 0.f, 0.f};
#pragma unroll
    for (int l = 0; l < L_SZ; ++l) {
        float4 ev = ((const float4*)enc)[l * 256 + tid];
        float wv = wts[l];
        s.x += wv * ev.x; s.y += wv * ev.y; s.z += wv * ev.z; s.w += wv * ev.w;
    }
    if (catf)  ((float4*)(catf + (size_t)b * 2 * H_SZ + H_SZ))[tid] = s;
    if (cat16) ((uint2*)(cat16 + (size_t)b * 2 * H_SZ + H_SZ))[tid] = pk4(s);
}

// ---------------------------------------------------------------------------
// GRU pointwise combine (+ optional bf16 copy of h_new for the big GEMM's A)
// ---------------------------------------------------------------------------
__global__ __launch_bounds__(256) void gru_combine(
    const float* __restrict__ gi, const float* __restrict__ gh,
    const float* __restrict__ hidden, float* __restrict__ h_new,
    short* __restrict__ hb16)
{
    int idx = blockIdx.x * blockDim.x + threadIdx.x;
    if (idx >= B_SZ * H_SZ) return;
    int b = idx >> 10;
    int j = idx & (H_SZ - 1);
    const float* gib = gi + (size_t)b * 3 * H_SZ;
    const float* ghb = gh + (size_t)b * 3 * H_SZ;
    float i_r = gib[j], i_z = gib[H_SZ + j], i_n = gib[2 * H_SZ + j];
    float h_r = ghb[j], h_z = ghb[H_SZ + j], h_n = ghb[2 * H_SZ + j];
    float r = 1.f / (1.f + expf(-(i_r + h_r)));
    float z = 1.f / (1.f + expf(-(i_z + h_z)));
    float n = tanhf(i_n + r * h_n);
    float h = hidden[idx];
    float hn = (1.f - z) * n + z * h;
    h_new[idx] = hn;
    if (hb16) hb16[idx] = (short)f2bf_bits(hn);
}

// ---------------------------------------------------------------------------
// log-softmax, 2 passes, float4, online max+sum, 4x-unrolled loads.
// ---------------------------------------------------------------------------
__global__ __launch_bounds__(1024) void logsoftmax_v3(float* __restrict__ out)
{
    const int b = blockIdx.x;
    float* row = out + (size_t)b * V_SZ;
    const int tid = threadIdx.x;
    const int wave = tid >> 6;
    const int lane = tid & 63;

    const int head = (int)(((16u - ((uintptr_t)row & 15u)) & 15u) >> 2);  // 0..3
    const int nv = (V_SZ - head) >> 2;
    const float4* r4 = (const float4*)(row + head);
    const int tail_start = head + (nv << 2);

    float m = -INFINITY, s = 0.f;
    if (tid < head) {
        float v = row[tid];
        m = v; s = 1.f;
    }
    int i = tid;
    for (; i + 3072 < nv; i += 4096) {
        float4 v0 = r4[i], v1 = r4[i + 1024], v2 = r4[i + 2048], v3 = r4[i + 3072];
        float m0 = fmaxf(fmaxf(v0.x, v0.y), fmaxf(v0.z, v0.w));
        float m1 = fmaxf(fmaxf(v1.x, v1.y), fmaxf(v1.z, v1.w));
        float m2 = fmaxf(fmaxf(v2.x, v2.y), fmaxf(v2.z, v2.w));
        float m3 = fmaxf(fmaxf(v3.x, v3.y), fmaxf(v3.z, v3.w));
        float mv = fmaxf(fmaxf(m0, m1), fmaxf(m2, m3));
        if (mv > m) { s *= expf(m - mv); m = mv; }
        s += expf(v0.x - m) + expf(v0.y - m) + expf(v0.z - m) + expf(v0.w - m);
        s += expf(v1.x - m) + expf(v1.y - m) + expf(v1.z - m) + expf(v1.w - m);
        s += expf(v2.x - m) + expf(v2.y - m) + expf(v2.z - m) + expf(v2.w - m);
        s += expf(v3.x - m) + expf(v3.y - m) + expf(v3.z - m) + expf(v3.w - m);
    }
    for (; i < nv; i += 1024) {
        float4 v = r4[i];
        float mv = fmaxf(fmaxf(v.x, v.y), fmaxf(v.z, v.w));
        if (mv > m) { s *= expf(m - mv); m = mv; }
        s += expf(v.x - m) + expf(v.y - m) + expf(v.z - m) + expf(v.w - m);
    }
    for (int t = tail_start + tid; t < V_SZ; t += 1024) {
        float v = row[t];
        if (v > m) { s *= expf(m - v); m = v; }
        s += expf(v - m);
    }

    for (int off = 32; off > 0; off >>= 1) {
        float m2 = __shfl_down(m, off);
        float s2 = __shfl_down(s, off);
        float mn = fmaxf(m, m2);
        s = s * expf(m - mn) + s2 * expf(m2 - mn);
        m = mn;
    }
    __shared__ float smax[16], ssum[16], slse;
    if (lane == 0) { smax[wave] = m; ssum[wave] = s; }
    __syncthreads();
    if (tid == 0) {
        float M = smax[0], S = ssum[0];
        for (int w = 1; w < 16; ++w) {
            float mn = fmaxf(M, smax[w]);
            S = S * expf(M - mn) + ssum[w] * expf(smax[w] - mn);
            M = mn;
        }
        slse = M + logf(S);
    }
    __syncthreads();
    const float lse = slse;

    if (tid < head) row[tid] -= lse;
    float4* w4 = (float4*)(row + head);
    i = tid;
    for (; i + 3072 < nv; i += 4096) {
        float4 v0 = r4[i], v1 = r4[i + 1024], v2 = r4[i + 2048], v3 = r4[i + 3072];
        v0.x -= lse; v0.y -= lse; v0.z -= lse; v0.w -= lse;
        v1.x -= lse; v1.y -= lse; v1.z -= lse; v1.w -= lse;
        v2.x -= lse; v2.y -= lse; v2.z -= lse; v2.w -= lse;
        v3.x -= lse; v3.y -= lse; v3.z -= lse; v3.w -= lse;
        w4[i] = v0; w4[i + 1024] = v1; w4[i + 2048] = v2; w4[i + 3072] = v3;
    }
    for (; i < nv; i += 1024) {
        float4 v = r4[i];
        v.x -= lse; v.y -= lse; v.z -= lse; v.w -= lse;
        w4[i] = v;
    }
    for (int t = tail_start + tid; t < V_SZ; t += 1024) row[t] -= lse;
}

// ---------------------------------------------------------------------------
extern "C" void kernel_launch(void* const* d_in, const int* in_sizes, int n_in,
                              void* d_out, int out_size, void* d_ws, size_t ws_size,
                              hipStream_t stream)
{
    const int*   tokens = (const int*)d_in[0];
    const float* hidden = (const float*)d_in[1];
    const float* enc    = (const float*)d_in[2];
    const float* emb    = (const float*)d_in[3];
    const float* attn_W = (const float*)d_in[4];
    const float* attn_b = (const float*)d_in[5];
    const float* comb_W = (const float*)d_in[6];
    const float* comb_b = (const float*)d_in[7];
    const float* W_ih   = (const float*)d_in[8];
    const float* W_hh   = (const float*)d_in[9];
    const float* b_ih   = (const float*)d_in[10];
    const float* b_hh   = (const float*)d_in[11];
    const float* out_W  = (const float*)d_in[12];
    const float* out_b  = (const float*)d_in[13];

    float* out = (float*)d_out;
    float* logits     = out;                                   // [B,V]
    float* h_new      = out + (size_t)B_SZ * V_SZ;             // [B,H]
    float* attn_w_out = h_new + (size_t)B_SZ * H_SZ;           // [B,L]

    const int NPANEL = (V_SZ + 31) / 32;                       // 1571

    // Workspace: bf16 A-operands (cat16, x16, hin16, hb16) + fp32 gi/gh.
    const size_t need = (size_t)B_SZ * 5 * H_SZ * sizeof(short)
                      + (size_t)B_SZ * 6 * H_SZ * sizeof(float);
    const bool use_ws = (d_ws != nullptr) && (ws_size >= need);

    if (use_ws) {
        short* cat16 = (short*)d_ws;                               // [B,2H]
        short* x16   = cat16 + (size_t)B_SZ * 2 * H_SZ;            // [B,H]
        short* hin16 = x16   + (size_t)B_SZ * H_SZ;                // [B,H]
        short* hb16  = hin16 + (size_t)B_SZ * H_SZ;                // [B,H]
        float* gi    = (float*)(hb16 + (size_t)B_SZ * H_SZ);       // [B,3H]
        float* gh    = gi + (size_t)B_SZ * 3 * H_SZ;               // [B,3H]

        attn_kernel<<<B_SZ, 256, 0, stream>>>(tokens, hidden, enc, emb, attn_W,
                                              attn_b, nullptr, cat16, hin16,
                                              attn_w_out);
        // x16 = bf16(relu(cat @ comb_W^T + comb_b))   [256 x 1024, K=2048]
        gemm_panel<1, 1, 2048, 1, 1><<<dim3(H_SZ / 16, 4), 256, 0, stream>>>(
            cat16, comb_W, comb_b, nullptr, x16, H_SZ);
        // gi = x @ W_ih^T + b_ih ; gh = h @ W_hh^T + b_hh   (one dispatch)
        gemm_panel_dual<1, 2, 1024, 1><<<dim3(3 * H_SZ / 32, 4, 2), 256, 0, stream>>>(
            x16, W_ih, b_ih, gi, hin16, W_hh, b_hh, gh, 3 * H_SZ);
        gru_combine<<<(B_SZ * H_SZ + 255) / 256, 256, 0, stream>>>(
            gi, gh, hidden, h_new, hb16);
        // logits = h_new @ out_W^T + out_b            [256 x 50257, K=1024]
        gemm_panel<4, 2, 1024, 0, 1><<<dim3(NPANEL, 1), 256, 0, stream>>>(
            hb16, out_W, out_b, logits, nullptr, V_SZ);
    } else {
        // Fallback: fp32 scratch carved from logits region (dead before the
        // big GEMM); big GEMM reads h_new (output region, safe) as fp32 A.
        float* cat = logits;                           // [B,2H]
        float* x   = cat + (size_t)B_SZ * 2 * H_SZ;    // [B,H]
        float* gi  = x   + (size_t)B_SZ * H_SZ;        // [B,3H]
        float* gh  = gi  + (size_t)B_SZ * 3 * H_SZ;    // [B,3H]

        attn_kernel<<<B_SZ, 256, 0, stream>>>(tokens, hidden, enc, emb, attn_W,
                                              attn_b, cat, nullptr, nullptr,
                                              attn_w_out);
        gemm_panel<1, 1, 2048, 1, 0><<<dim3(H_SZ / 16, 4), 256, 0, stream>>>(
            cat, comb_W, comb_b, x, nullptr, H_SZ);
        gemm_panel_dual<1, 2, 1024, 0><<<dim3(3 * H_SZ / 32, 4, 2), 256, 0, stream>>>(
            x, W_ih, b_ih, gi, hidden, W_hh, b_hh, gh, 3 * H_SZ);
        gru_combine<<<(B_SZ * H_SZ + 255) / 256, 256, 0, stream>>>(
            gi, gh, hidden, h_new, nullptr);
        gemm_panel<4, 2, 1024, 0, 0><<<dim3(NPANEL, 1), 256, 0, stream>>>(
            h_new, out_W, out_b, logits, nullptr, V_SZ);
    }
    logsoftmax_v3<<<B_SZ, 1024, 0, stream>>>(logits);
}